// Round 11
// baseline (203.360 us; speedup 1.0000x reference)
//
#include <hip/hip_runtime.h>
#include <hip/hip_bf16.h>

#define NB 8
#define NQ 16
#define NP 4096
#define NHID 4096
#define NHEADS 32
#define NKVH 8
#define NG 4
#define ND 128
#define NM 128          // NB*NQ
#define NSEQ 4112       // NP+NQ
#define N_QKV 6144
#define SPLITK 8
#define NS 8            // key splits (grid.y); combine slots = NS*2 (per key-half)

typedef __attribute__((ext_vector_type(8))) short bf16x8;
typedef __attribute__((ext_vector_type(4))) float f32x4;

__device__ __forceinline__ unsigned short f2bf(float f) {
  unsigned int u = __float_as_uint(f);
  u = (u + 0x7FFFu + ((u >> 16) & 1u)) >> 16;
  return (unsigned short)u;
}

__device__ __forceinline__ unsigned cvtpk(float lo, float hi) {
  unsigned r;
  asm("v_cvt_pk_bf16_f32 %0, %1, %2" : "=v"(r) : "v"(lo), "v"(hi));
  return r;
}

__device__ __forceinline__ float bf2f(unsigned short u) {
  return __uint_as_float(((unsigned)u) << 16);
}

#define TRREAD(dst, a32) \
  asm volatile("ds_read_b64_tr_b16 %0, %1" : "=v"(dst) : "v"(a32))
#define LGKM0() asm volatile("s_waitcnt lgkmcnt(0)" ::: "memory")
#define SBAR()                              \
  do {                                      \
    __builtin_amdgcn_sched_barrier(0);      \
    __builtin_amdgcn_s_barrier();           \
    __builtin_amdgcn_sched_barrier(0);      \
  } while (0)

// ---------------- hidden fp32 -> bf16 ----------------
__global__ __launch_bounds__(256) void k_cvt(const float* __restrict__ x,
                                             unsigned short* __restrict__ y, int n4) {
  int i = blockIdx.x * 256 + threadIdx.x;
  if (i >= n4) return;
  f32x4 v = ((const f32x4*)x)[i];
  uint2 o;
  o.x = cvtpk(v[0], v[1]);
  o.y = cvtpk(v[2], v[3]);
  ((uint2*)y)[i] = o;
}

// ---------------- split-K MFMA GEMM: A[128][lda] bf16 @ W[K][N] fp32 -> partials ----
template<int CT>
__global__ __launch_bounds__(256) void k_gemm(
    const unsigned short* __restrict__ A, int lda,
    const float* __restrict__ W0, const float* __restrict__ W1,
    const float* __restrict__ W2, int nw0, int nw1, int N, int KS,
    float* __restrict__ part) {
  constexpr int BN = CT * 32;
  constexpr int NT = CT * 2;
  constexpr int NW4 = BN / 4;
  constexpr int KST = 256 / NW4;
  __shared__ __align__(16) char Bl[8 * NT * 128];
  int n0 = blockIdx.x * BN;
  int k0 = blockIdx.y * KS;
  const float* Wp; int ldw, ncol;
  if (n0 < nw0)      { Wp = W0; ldw = nw0;       ncol = n0; }
  else if (n0 < nw1) { Wp = W1; ldw = nw1 - nw0; ncol = n0 - nw0; }
  else               { Wp = W2; ldw = N - nw1;   ncol = n0 - nw1; }
  int tid = threadIdx.x, lane = tid & 63, wid = tid >> 6;
  int r16 = lane & 15, hi = lane >> 4;
  int wr = wid >> 1, wc = wid & 1;
  int n4 = tid & (NW4 - 1), krow = tid / NW4;
  unsigned lb = (unsigned)(uintptr_t)(void*)Bl;

  f32x4 acc[4][CT];
#pragma unroll
  for (int i = 0; i < 4; ++i)
#pragma unroll
    for (int j = 0; j < CT; ++j) acc[i][j] = {0.f, 0.f, 0.f, 0.f};

  f32x4 cur[CT], nxt[CT];
#pragma unroll
  for (int r = 0; r < CT; ++r) {
    cur[r] = *(const f32x4*)&Wp[(size_t)(k0 + krow + r * KST) * ldw + ncol + n4 * 4];
    nxt[r] = cur[r];
  }

  for (int kk = 0; kk < KS; kk += 32) {
    SBAR();
    if (kk + 32 < KS) {
#pragma unroll
      for (int r = 0; r < CT; ++r)
        nxt[r] = *(const f32x4*)&Wp[(size_t)(k0 + kk + 32 + krow + r * KST) * ldw + ncol + n4 * 4];
    }
#pragma unroll
    for (int r = 0; r < CT; ++r) {
      int k = krow + r * KST;
      uint2 u;
      u.x = cvtpk(cur[r][0], cur[r][1]);
      u.y = cvtpk(cur[r][2], cur[r][3]);
      *(uint2*)(Bl + ((k >> 2) * NT + (n4 >> 2)) * 128 + (k & 3) * 32 + (n4 & 3) * 8) = u;
    }
    LGKM0();
    SBAR();
    bf16x8 af[4];
#pragma unroll
    for (int rt = 0; rt < 4; ++rt)
      af[rt] = *(const bf16x8*)&A[(size_t)(wr * 64 + rt * 16 + r16) * lda + k0 + kk + hi * 8];
    unsigned long long rr[2 * CT];
#pragma unroll
    for (int ct = 0; ct < CT; ++ct) {
      int s1 = hi * (2 * NT) + wc * CT + ct;
      TRREAD(rr[ct * 2],     lb + s1 * 128 + r16 * 8);
      TRREAD(rr[ct * 2 + 1], lb + (s1 + NT) * 128 + r16 * 8);
    }
    LGKM0();
    __builtin_amdgcn_sched_barrier(0);
    __builtin_amdgcn_s_setprio(1);
#pragma unroll
    for (int ct = 0; ct < CT; ++ct) {
      union { unsigned long long u[2]; bf16x8 v; } cc;
      cc.u[0] = rr[ct * 2]; cc.u[1] = rr[ct * 2 + 1];
#pragma unroll
      for (int rt = 0; rt < 4; ++rt)
        acc[rt][ct] = __builtin_amdgcn_mfma_f32_16x16x32_bf16(af[rt], cc.v, acc[rt][ct], 0, 0, 0);
    }
    __builtin_amdgcn_s_setprio(0);
#pragma unroll
    for (int r = 0; r < CT; ++r) cur[r] = nxt[r];
  }
  float* po = part + (size_t)blockIdx.y * NM * N;
#pragma unroll
  for (int rt = 0; rt < 4; ++rt)
#pragma unroll
    for (int ct = 0; ct < CT; ++ct)
#pragma unroll
      for (int r = 0; r < 4; ++r) {
        int m = wr * 64 + rt * 16 + hi * 4 + r;
        int n = n0 + wc * CT * 16 + ct * 16 + r16;
        po[(size_t)m * N + n] = acc[rt][ct][r];
      }
}

// ---------------- reduce QKV partials + RoPE + scale-fold -> bf16 q/k/v ----------------
__global__ __launch_bounds__(256) void k_rope(
    const float* __restrict__ part, const void* __restrict__ posv,
    unsigned short* __restrict__ qb, unsigned short* __restrict__ kb,
    unsigned short* __restrict__ vb) {
  int t = blockIdx.x * 256 + threadIdx.x;
  int d = t & 63;
  int rest = t >> 6;
  int h = rest % 48;
  int m = rest / 48;
  if (m >= NM) return;
  const int* p32 = (const int*)posv;
  const long long* p64 = (const long long*)posv;
  bool is64 = (p64[0] == (long long)p32[0]);
  int pos = is64 ? (int)p64[m] : p32[m];
  int b = m >> 4, q = m & 15;

  int c1, c2;
  if (h < 32)      { c1 = h * ND + d; }
  else if (h < 40) { c1 = NHID + (h - 32) * ND + d; }
  else             { c1 = NHID + 1024 + (h - 40) * ND + d; }
  c2 = c1 + 64;
  float x1 = 0.f, x2 = 0.f;
#pragma unroll
  for (int c = 0; c < SPLITK; ++c) {
    x1 += part[((size_t)c * NM + m) * N_QKV + c1];
    x2 += part[((size_t)c * NM + m) * N_QKV + c2];
  }
  if (h < 40) {
    float invf = __expf(-(float)d * 0.14391156831212787f);  // ln(10000)/64
    float th = (float)pos * invf;
    float cs = cosf(th), sn = sinf(th);
    float o1 = x1 * cs - x2 * sn;
    float o2 = x2 * cs + x1 * sn;
    if (h < 32) {
      o1 *= 0.08838834764831845f;  // 1/sqrt(128)
      o2 *= 0.08838834764831845f;
      int kv = h >> 2, g = h & 3;
      size_t base = ((((size_t)b * NKVH + kv) * NG + g) * NQ + q) * ND;
      qb[base + d] = f2bf(o1);
      qb[base + d + 64] = f2bf(o2);
    } else {
      int kvh = h - 32;
      size_t base = (((size_t)b * NKVH + kvh) * NQ + q) * ND;
      kb[base + d] = f2bf(o1);
      kb[base + d + 64] = f2bf(o2);
    }
  } else {
    int kvh = h - 40;
    size_t base = (((size_t)b * NKVH + kvh) * NQ + q) * ND;
    vb[base + d] = f2bf(x1);
    vb[base + d + 64] = f2bf(x2);
  }
}

// ---------------- flash attention: 512 threads, 8 waves = 4 heads x 2 key-halves ----
// LDS 81920 B (2 blocks/CU -> 16 waves/CU = 4/SIMD):
//   K0@0 K1@16384 V0@32768 V1@49152 (64-key bf16 tiles; layouts as before)
//   P @ 65536 (8 KB: per-wave 1 KB [q][j2<32]: byte = q*64 + ((j2*2)^((q&3)<<4)))
//   bias0 @ 73728, bias1 @ 77824 (4 KB fp32: byte = q*256 + ((j*4)^((q&7)<<4)))
// Wave (g=wid&3, half=wid>>2): head g, keys [half*32, half*32+32) of the tile.
// Each wave's partial (m,l,o) goes to combine slot split*2+half (16 slots).
template<int NSPL>
__global__ __launch_bounds__(512, 4) void k_attn(
    const unsigned short* __restrict__ qb, const unsigned short* __restrict__ kb,
    const unsigned short* __restrict__ vb, const float* __restrict__ pastK,
    const float* __restrict__ pastV, const float* __restrict__ bias,
    unsigned short* __restrict__ pout, float* __restrict__ pml) {
  __shared__ __align__(16) char lds[81920];
  char* Pl = lds + 65536;
  constexpr int KEYS = NP / NSPL;      // 512
  constexpr int NSUB = KEYS / 64;      // 8
  int bkv = blockIdx.x;
  int split = blockIdx.y;
  int b = bkv >> 3, kv = bkv & 7;
  int tid = threadIdx.x, lane = tid & 63, wid = tid >> 6;
  int r16 = lane & 15, hi = lane >> 4;
  int g = wid & 3, half = wid >> 2;

  const unsigned short* qbase = qb + ((((size_t)b * NKVH + kv) * NG + g) * NQ) * ND;
  bf16x8 qf[4];
#pragma unroll
  for (int kd = 0; kd < 4; ++kd)
    qf[kd] = *(const bf16x8*)&qbase[r16 * ND + kd * 32 + hi * 8];

  float m_run[4], l_lane[4];
  f32x4 oacc[8];
#pragma unroll
  for (int r = 0; r < 4; ++r) { m_run[r] = -1e30f; l_lane[r] = 0.f; }
#pragma unroll
  for (int dt = 0; dt < 8; ++dt) oacc[dt] = {0.f, 0.f, 0.f, 0.f};

  int s0 = split * KEYS;
  const float* Kg = pastK + ((size_t)(b * NKVH + kv) * NP + s0) * ND;
  const float* Vg = pastV + ((size_t)(b * NKVH + kv) * NP + s0) * ND;
  const float* biasrow = bias + (size_t)(b * NQ) * NSEQ;
  int d4 = tid & 31, sr = tid >> 5;    // 32 lanes/row, 16 rows/round, 4 rounds
  bool last = (split == NSPL - 1);

  f32x4 rwK[4], rwV[4];
  float br0, br1, bt[4];
  bf16x8 tk, tv;

  auto kissue = [&](int tile) {
    const float* Kn = Kg + (size_t)tile * 64 * ND;
#pragma unroll
    for (int it = 0; it < 4; ++it)
      rwK[it] = *(const f32x4*)&Kn[(size_t)(sr + it * 16) * ND + d4 * 4];
  };
  auto vissue = [&](int tile) {
    const float* Vn = Vg + (size_t)tile * 64 * ND;
#pragma unroll
    for (int it = 0; it < 4; ++it)
      rwV[it] = *(const f32x4*)&Vn[(size_t)(sr + it * 16) * ND + d4 * 4];
  };
  auto bissue = [&](int tile) {
    {
      int e = tid;        int q = e >> 6, j = e & 63;
      br0 = biasrow[(size_t)q * NSEQ + s0 + tile * 64 + j];
    }
    {
      int e = 512 + tid;  int q = e >> 6, j = e & 63;
      br1 = biasrow[(size_t)q * NSEQ + s0 + tile * 64 + j];
    }
  };
  auto kconv = [&](char* Kl) {
#pragma unroll
    for (int it = 0; it < 4; ++it) {
      int s = sr + it * 16;
      uint2 u;
      u.x = cvtpk(rwK[it][0], rwK[it][1]); u.y = cvtpk(rwK[it][2], rwK[it][3]);
      *(uint2*)(Kl + s * 256 + ((d4 * 8) ^ ((s & 7) << 4))) = u;
    }
  };
  auto vconv = [&](char* Vl) {
#pragma unroll
    for (int it = 0; it < 4; ++it) {
      int s = sr + it * 16;
      uint2 u;
      u.x = cvtpk(rwV[it][0], rwV[it][1]); u.y = cvtpk(rwV[it][2], rwV[it][3]);
      *(uint2*)(Vl + ((s >> 2) * 8 + (d4 >> 2)) * 128 + (s & 3) * 32 + (d4 & 3) * 8) = u;
    }
  };
  auto bstore = [&](char* Bb) {
    {
      int e = tid;        int q = e >> 6, j = e & 63;
      *(float*)(Bb + q * 256 + ((j * 4) ^ ((q & 7) << 4))) = br0;
    }
    {
      int e = 512 + tid;  int q = e >> 6, j = e & 63;
      *(float*)(Bb + q * 256 + ((j * 4) ^ ((q & 7) << 4))) = br1;
    }
  };

  f32x4 sc[2];
  auto qk_softmax = [&](char* Kl, char* Bb, bool tail) {
    __builtin_amdgcn_s_setprio(1);
#pragma unroll
    for (int ct = 0; ct < 2; ++ct) {
      f32x4 a = {0.f, 0.f, 0.f, 0.f};
      int s = half * 32 + ct * 16 + r16;
#pragma unroll
      for (int kd = 0; kd < 4; ++kd) {
        bf16x8 kf = *(const bf16x8*)(Kl + s * 256 + ((kd * 64 + hi * 16) ^ ((s & 7) << 4)));
        a = __builtin_amdgcn_mfma_f32_16x16x32_bf16(qf[kd], kf, a, 0, 0, 0);
      }
      sc[ct] = a;
    }
    __builtin_amdgcn_s_setprio(0);
    if (!tail) {
#pragma unroll
      for (int ct = 0; ct < 2; ++ct)
#pragma unroll
        for (int r = 0; r < 4; ++r) {
          int q = hi * 4 + r, j = half * 32 + ct * 16 + r16;
          sc[ct][r] += *(const float*)(Bb + q * 256 + ((j * 4) ^ ((q & 7) << 4)));
        }
    } else {  // tail: only half==0 waves; keys j2 = r16 < 16 valid
#pragma unroll
      for (int ct = 0; ct < 2; ++ct)
#pragma unroll
        for (int r = 0; r < 4; ++r) {
          if (ct == 0) sc[ct][r] += bt[r];
          else         sc[ct][r] = -1e30f;
        }
    }
    float pmax[4];
#pragma unroll
    for (int r = 0; r < 4; ++r)
      pmax[r] = fmaxf(sc[0][r], sc[1][r]);
    bool ok = (pmax[0] <= m_run[0] + 8.f) && (pmax[1] <= m_run[1] + 8.f) &&
              (pmax[2] <= m_run[2] + 8.f) && (pmax[3] <= m_run[3] + 8.f);
    if (!__all(ok)) {   // slow path (rare)
#pragma unroll
      for (int r = 0; r < 4; ++r) {
        float v = pmax[r];
        v = fmaxf(v, __shfl_xor(v, 1));
        v = fmaxf(v, __shfl_xor(v, 2));
        v = fmaxf(v, __shfl_xor(v, 4));
        v = fmaxf(v, __shfl_xor(v, 8));
        float mnew = fmaxf(m_run[r], v);
        float fac = __expf(m_run[r] - mnew);
        m_run[r] = mnew;
        l_lane[r] *= fac;
#pragma unroll
        for (int dt = 0; dt < 8; ++dt) oacc[dt][r] *= fac;
      }
    }
#pragma unroll
    for (int ct = 0; ct < 2; ++ct)
#pragma unroll
      for (int r = 0; r < 4; ++r) {
        float p = __expf(sc[ct][r] - m_run[r]);
        l_lane[r] += p;
        int q = hi * 4 + r, j2 = ct * 16 + r16;
        *(unsigned short*)(Pl + wid * 1024 + q * 64 + ((j2 * 2) ^ ((q & 3) << 4))) = f2bf(p);
      }
  };

  auto pv = [&](char* Vl) {
    unsigned vb32 = (unsigned)(uintptr_t)(void*)Vl;
    bf16x8 pa = *(const bf16x8*)(Pl + wid * 1024 + r16 * 64 +
                                 ((hi * 16) ^ ((r16 & 3) << 4)));
#pragma unroll
    for (int dh = 0; dh < 2; ++dh) {
      unsigned long long rr[8];
#pragma unroll
      for (int dq = 0; dq < 4; ++dq) {
        int sA = half * 64 + hi * 16 + dh * 4 + dq;
        TRREAD(rr[dq * 2],     vb32 + sA * 128 + r16 * 8);
        TRREAD(rr[dq * 2 + 1], vb32 + (sA + 8) * 128 + r16 * 8);
      }
      LGKM0();
      __builtin_amdgcn_sched_barrier(0);
      __builtin_amdgcn_s_setprio(1);
#pragma unroll
      for (int dq = 0; dq < 4; ++dq) {
        union { unsigned long long u[2]; bf16x8 v; } cc;
        cc.u[0] = rr[dq * 2]; cc.u[1] = rr[dq * 2 + 1];
        oacc[dh * 4 + dq] = __builtin_amdgcn_mfma_f32_16x16x32_bf16(pa, cc.v, oacc[dh * 4 + dq], 0, 0, 0);
      }
      __builtin_amdgcn_s_setprio(0);
    }
  };

  // ---- prologue: tile0 -> buf0 ----
  kissue(0);
  vissue(0);
  bissue(0);
  kconv(lds + 0);
  vconv(lds + 32768);
  bstore(lds + 73728);
  LGKM0();

  // ---- main loop ----
  int cur = 0;
  for (int sub = 0; sub < NSUB; ++sub) {
    char* KlC = lds + cur * 16384;
    char* VlC = lds + 32768 + cur * 16384;
    char* BbC = lds + 73728 + cur * 4096;
    char* KlN = lds + (cur ^ 1) * 16384;
    char* VlN = lds + 32768 + (cur ^ 1) * 16384;
    char* BbN = lds + 73728 + (cur ^ 1) * 4096;
    SBAR();                                  // buf[cur] ready
    bool pf = (sub + 1 < NSUB);
    if (pf) {                                // issue next K + bias (V issued mid-iter)
      kissue(sub + 1);
      bissue(sub + 1);
    } else if (last) {                       // issue tail (16 new bf16 keys)
      if (tid < 256) {
        int s = tid >> 4, d8 = tid & 15;
        const unsigned short* Kn = kb + (((size_t)b * NKVH + kv) * NQ) * ND;
        const unsigned short* Vn = vb + (((size_t)b * NKVH + kv) * NQ) * ND;
        tk = *(const bf16x8*)&Kn[s * ND + d8 * 8];
        tv = *(const bf16x8*)&Vn[s * ND + d8 * 8];
      }
      if (half == 0) {
#pragma unroll
        for (int r = 0; r < 4; ++r)
          bt[r] = biasrow[(size_t)(hi * 4 + r) * NSEQ + NP + r16];
      }
    }
    qk_softmax(KlC, BbC, false);
    if (pf) {
      kconv(KlN);                            // waits this iter's K only
      vissue(sub + 1);                       // V flies under pv
    } else if (last) {
      if (tid < 256) {
        int s = tid >> 4, d8 = tid & 15;
        *(bf16x8*)(KlN + s * 256 + ((d8 * 16) ^ ((s & 7) << 4))) = tk;
      }
    }
    pv(VlC);
    if (pf) {
      vconv(VlN);                            // waits V only (bias older: done)
      bstore(BbN);
    } else if (last) {
      if (tid < 256) {
        int s = tid >> 4, d8 = tid & 15;
        *(bf16x8*)(VlN + ((s >> 2) * 8 + (d8 >> 1)) * 128 + (s & 3) * 32 + (d8 & 1) * 16) = tv;
      }
    }
    LGKM0();                                 // ds writes visible before next SBAR
    if (pf || last) cur ^= 1;
  }
  if (last) {                                // tail keys in buf[cur]; half==0 waves only
    SBAR();
    if (half == 0) {
      qk_softmax(lds + cur * 16384, (char*)0, true);
      pv(lds + 32768 + cur * 16384);
    }
  }

  // ---- epilogue: reduce l partials; bounce oacc through lds; coalesced stores ----
  float l_run[4];
#pragma unroll
  for (int r = 0; r < 4; ++r) {
    float s = l_lane[r];
    s += __shfl_xor(s, 1);
    s += __shfl_xor(s, 2);
    s += __shfl_xor(s, 4);
    s += __shfl_xor(s, 8);
    l_run[r] = s;
  }
  SBAR();
  char* My = lds + wid * 4096;
#pragma unroll
  for (int dt = 0; dt < 8; ++dt)
#pragma unroll
    for (int r = 0; r < 4; ++r)
      *(unsigned short*)(My + (hi * 4 + r) * 256 + (dt * 16 + r16) * 2) = f2bf(oacc[dt][r]);
  LGKM0();
  const int NROW = NB * NKVH * NG * NQ;      // 8192
  int slot = split * 2 + half;
  size_t rowbase = ((size_t)(b * NKVH + kv) * NG + g) * NQ;
  unsigned short* po = pout + ((size_t)slot * NROW + rowbase) * ND;
#pragma unroll
  for (int it = 0; it < 4; ++it) {
    int row = it * 4 + (lane >> 4);
    uint4 vv = *(uint4*)(My + row * 256 + r16 * 16);
    *(uint4*)&po[(size_t)row * ND + r16 * 8] = vv;
  }
  if (r16 == 0) {
#pragma unroll
    for (int r = 0; r < 4; ++r) {
      size_t idx = ((size_t)slot * NROW + rowbase + hi * 4 + r) * 2;
      pml[idx] = m_run[r];
      pml[idx + 1] = l_run[r];
    }
  }
}

// ---------------- combine split partials -> bf16 A for the Wo GEMM ----------------
template<int NSPL>
__global__ __launch_bounds__(256) void k_combine(
    const unsigned short* __restrict__ pout, const float* __restrict__ pml,
    unsigned short* __restrict__ Aatt) {
  const int NROW = NB * NKVH * NG * NQ;  // 8192
  int row = blockIdx.x * 2 + (threadIdx.x >> 7);
  int d = threadIdx.x & 127;
  float mv[NSPL], lv[NSPL];
  float M = -1e30f;
#pragma unroll
  for (int c = 0; c < NSPL; ++c) {
    mv[c] = pml[((size_t)c * NROW + row) * 2];
    lv[c] = pml[((size_t)c * NROW + row) * 2 + 1];
    M = fmaxf(M, mv[c]);
  }
  float L = 0.f, acc = 0.f;
#pragma unroll
  for (int c = 0; c < NSPL; ++c) {
    float w = __expf(mv[c] - M);
    L += lv[c] * w;
    acc += bf2f(pout[((size_t)c * NROW + row) * ND + d]) * w;
  }
  float o = acc / L;
  int q = row & 15, g = (row >> 4) & 3, kvh = (row >> 6) & 7, b = row >> 9;
  Aatt[(size_t)(b * NQ + q) * NHID + (kvh * NG + g) * ND + d] = f2bf(o);
}

// ---------------- reduce Wo partials -> d_out ----------------
__global__ __launch_bounds__(256) void k_red(const float* __restrict__ part,
                                             float* __restrict__ out) {
  int i = blockIdx.x * 256 + threadIdx.x;
  float s = 0.f;
#pragma unroll
  for (int c = 0; c < SPLITK; ++c) s += part[(size_t)c * (NM * NHID) + i];
  out[i] = s;
}

extern "C" void kernel_launch(void* const* d_in, const int* in_sizes, int n_in,
                              void* d_out, int out_size, void* d_ws, size_t ws_size,
                              hipStream_t stream) {
  const float* hidden = (const float*)d_in[0];
  const void* pos = d_in[1];
  const float* pastK = (const float*)d_in[2];
  const float* pastV = (const float*)d_in[3];
  const float* bias = (const float*)d_in[4];
  const float* Wq = (const float*)d_in[5];
  const float* Wk = (const float*)d_in[6];
  const float* Wv = (const float*)d_in[7];
  const float* Wo = (const float*)d_in[8];
  float* out = (float*)d_out;

  char* ws = (char*)d_ws;
  size_t off = 0;
  auto alloc = [&](size_t bytes) {
    char* p = ws + off;
    off += (bytes + 255) & ~(size_t)255;
    return p;
  };
  unsigned short* hb   = (unsigned short*)alloc((size_t)NM * NHID * 2);
  unsigned short* qb   = (unsigned short*)alloc((size_t)NB * NKVH * NG * NQ * ND * 2);
  unsigned short* kb   = (unsigned short*)alloc((size_t)NB * NKVH * NQ * ND * 2);
  unsigned short* vb   = (unsigned short*)alloc((size_t)NB * NKVH * NQ * ND * 2);
  unsigned short* Aatt = (unsigned short*)alloc((size_t)NM * NHID * 2);

  // Union region: GEMM partials (phases 1 & 5) alias attn pml+pout (phases 3-4).
  size_t mlB = (size_t)(NS * 2) * 8192 * 2 * 4;   // 16 combine slots
  float* pml = (float*)(ws + off);
  unsigned short* pout = (unsigned short*)(ws + off + mlB);
  float* part = (float*)(ws + off);

  k_cvt<<<512, 256, 0, stream>>>(hidden, hb, NM * NHID / 4);
  k_gemm<2><<<dim3(96, SPLITK), 256, 0, stream>>>(hb, NHID, Wq, Wk, Wv, 4096, 5120,
                                                  N_QKV, NHID / SPLITK, part);
  k_rope<<<1536, 256, 0, stream>>>(part, pos, qb, kb, vb);
  k_attn<NS><<<dim3(64, NS), 512, 0, stream>>>(qb, kb, vb, pastK, pastV, bias, pout, pml);
  k_combine<NS * 2><<<4096, 256, 0, stream>>>(pout, pml, Aatt);
  k_gemm<2><<<dim3(64, SPLITK), 256, 0, stream>>>(Aatt, NHID, Wo, Wo, Wo, 4096, 8192,
                                                  NHID, NHID / SPLITK, part);
  k_red<<<2048, 256, 0, stream>>>(part, out);
}

// Round 12
// 152.877 us; speedup vs baseline: 1.3302x; 1.3302x over previous
//
#include <hip/hip_runtime.h>
#include <hip/hip_bf16.h>

#define NB 8
#define NQ 16
#define NP 4096
#define NHID 4096
#define NHEADS 32
#define NKVH 8
#define NG 4
#define ND 128
#define NM 128          // NB*NQ
#define NSEQ 4112       // NP+NQ
#define N_QKV 6144
#define SPLITK 8
#define NS 16           // key splits (grid.y); KVBLK=32

typedef __attribute__((ext_vector_type(8))) short bf16x8;
typedef __attribute__((ext_vector_type(4))) float f32x4;

__device__ __forceinline__ unsigned short f2bf(float f) {
  unsigned int u = __float_as_uint(f);
  u = (u + 0x7FFFu + ((u >> 16) & 1u)) >> 16;
  return (unsigned short)u;
}

__device__ __forceinline__ unsigned cvtpk(float lo, float hi) {
  unsigned r;
  asm("v_cvt_pk_bf16_f32 %0, %1, %2" : "=v"(r) : "v"(lo), "v"(hi));
  return r;
}

__device__ __forceinline__ float bf2f(unsigned short u) {
  return __uint_as_float(((unsigned)u) << 16);
}

#define TRREAD(dst, a32) \
  asm volatile("ds_read_b64_tr_b16 %0, %1" : "=v"(dst) : "v"(a32))
#define LGKM0() asm volatile("s_waitcnt lgkmcnt(0)" ::: "memory")
#define SBAR()                              \
  do {                                      \
    __builtin_amdgcn_sched_barrier(0);      \
    __builtin_amdgcn_s_barrier();           \
    __builtin_amdgcn_sched_barrier(0);      \
  } while (0)

// ---------------- hidden fp32 -> bf16 ----------------
__global__ __launch_bounds__(256) void k_cvt(const float* __restrict__ x,
                                             unsigned short* __restrict__ y, int n4) {
  int i = blockIdx.x * 256 + threadIdx.x;
  if (i >= n4) return;
  f32x4 v = ((const f32x4*)x)[i];
  uint2 o;
  o.x = cvtpk(v[0], v[1]);
  o.y = cvtpk(v[2], v[3]);
  ((uint2*)y)[i] = o;
}

// ---------------- split-K MFMA GEMM: A[128][lda] bf16 @ W[K][N] fp32 -> partials ----
template<int CT>
__global__ __launch_bounds__(256) void k_gemm(
    const unsigned short* __restrict__ A, int lda,
    const float* __restrict__ W0, const float* __restrict__ W1,
    const float* __restrict__ W2, int nw0, int nw1, int N, int KS,
    float* __restrict__ part) {
  constexpr int BN = CT * 32;
  constexpr int NT = CT * 2;
  constexpr int NW4 = BN / 4;
  constexpr int KST = 256 / NW4;
  __shared__ __align__(16) char Bl[8 * NT * 128];
  int n0 = blockIdx.x * BN;
  int k0 = blockIdx.y * KS;
  const float* Wp; int ldw, ncol;
  if (n0 < nw0)      { Wp = W0; ldw = nw0;       ncol = n0; }
  else if (n0 < nw1) { Wp = W1; ldw = nw1 - nw0; ncol = n0 - nw0; }
  else               { Wp = W2; ldw = N - nw1;   ncol = n0 - nw1; }
  int tid = threadIdx.x, lane = tid & 63, wid = tid >> 6;
  int r16 = lane & 15, hi = lane >> 4;
  int wr = wid >> 1, wc = wid & 1;
  int n4 = tid & (NW4 - 1), krow = tid / NW4;
  unsigned lb = (unsigned)(uintptr_t)(void*)Bl;

  f32x4 acc[4][CT];
#pragma unroll
  for (int i = 0; i < 4; ++i)
#pragma unroll
    for (int j = 0; j < CT; ++j) acc[i][j] = {0.f, 0.f, 0.f, 0.f};

  f32x4 cur[CT], nxt[CT];
#pragma unroll
  for (int r = 0; r < CT; ++r) {
    cur[r] = *(const f32x4*)&Wp[(size_t)(k0 + krow + r * KST) * ldw + ncol + n4 * 4];
    nxt[r] = cur[r];
  }

  for (int kk = 0; kk < KS; kk += 32) {
    SBAR();
    if (kk + 32 < KS) {
#pragma unroll
      for (int r = 0; r < CT; ++r)
        nxt[r] = *(const f32x4*)&Wp[(size_t)(k0 + kk + 32 + krow + r * KST) * ldw + ncol + n4 * 4];
    }
#pragma unroll
    for (int r = 0; r < CT; ++r) {
      int k = krow + r * KST;
      uint2 u;
      u.x = cvtpk(cur[r][0], cur[r][1]);
      u.y = cvtpk(cur[r][2], cur[r][3]);
      *(uint2*)(Bl + ((k >> 2) * NT + (n4 >> 2)) * 128 + (k & 3) * 32 + (n4 & 3) * 8) = u;
    }
    LGKM0();
    SBAR();
    bf16x8 af[4];
#pragma unroll
    for (int rt = 0; rt < 4; ++rt)
      af[rt] = *(const bf16x8*)&A[(size_t)(wr * 64 + rt * 16 + r16) * lda + k0 + kk + hi * 8];
    unsigned long long rr[2 * CT];
#pragma unroll
    for (int ct = 0; ct < CT; ++ct) {
      int s1 = hi * (2 * NT) + wc * CT + ct;
      TRREAD(rr[ct * 2],     lb + s1 * 128 + r16 * 8);
      TRREAD(rr[ct * 2 + 1], lb + (s1 + NT) * 128 + r16 * 8);
    }
    LGKM0();
    __builtin_amdgcn_sched_barrier(0);
    __builtin_amdgcn_s_setprio(1);
#pragma unroll
    for (int ct = 0; ct < CT; ++ct) {
      union { unsigned long long u[2]; bf16x8 v; } cc;
      cc.u[0] = rr[ct * 2]; cc.u[1] = rr[ct * 2 + 1];
#pragma unroll
      for (int rt = 0; rt < 4; ++rt)
        acc[rt][ct] = __builtin_amdgcn_mfma_f32_16x16x32_bf16(af[rt], cc.v, acc[rt][ct], 0, 0, 0);
    }
    __builtin_amdgcn_s_setprio(0);
#pragma unroll
    for (int r = 0; r < CT; ++r) cur[r] = nxt[r];
  }
  float* po = part + (size_t)blockIdx.y * NM * N;
#pragma unroll
  for (int rt = 0; rt < 4; ++rt)
#pragma unroll
    for (int ct = 0; ct < CT; ++ct)
#pragma unroll
      for (int r = 0; r < 4; ++r) {
        int m = wr * 64 + rt * 16 + hi * 4 + r;
        int n = n0 + wc * CT * 16 + ct * 16 + r16;
        po[(size_t)m * N + n] = acc[rt][ct][r];
      }
}

// ---------------- reduce QKV partials + RoPE + scale-fold -> bf16 q/k/v ----------------
__global__ __launch_bounds__(256) void k_rope(
    const float* __restrict__ part, const void* __restrict__ posv,
    unsigned short* __restrict__ qb, unsigned short* __restrict__ kb,
    unsigned short* __restrict__ vb) {
  int t = blockIdx.x * 256 + threadIdx.x;
  int d = t & 63;
  int rest = t >> 6;
  int h = rest % 48;
  int m = rest / 48;
  if (m >= NM) return;
  const int* p32 = (const int*)posv;
  const long long* p64 = (const long long*)posv;
  bool is64 = (p64[0] == (long long)p32[0]);
  int pos = is64 ? (int)p64[m] : p32[m];
  int b = m >> 4, q = m & 15;

  int c1, c2;
  if (h < 32)      { c1 = h * ND + d; }
  else if (h < 40) { c1 = NHID + (h - 32) * ND + d; }
  else             { c1 = NHID + 1024 + (h - 40) * ND + d; }
  c2 = c1 + 64;
  float x1 = 0.f, x2 = 0.f;
#pragma unroll
  for (int c = 0; c < SPLITK; ++c) {
    x1 += part[((size_t)c * NM + m) * N_QKV + c1];
    x2 += part[((size_t)c * NM + m) * N_QKV + c2];
  }
  if (h < 40) {
    float invf = __expf(-(float)d * 0.14391156831212787f);  // ln(10000)/64
    float th = (float)pos * invf;
    float cs = cosf(th), sn = sinf(th);
    float o1 = x1 * cs - x2 * sn;
    float o2 = x2 * cs + x1 * sn;
    if (h < 32) {
      o1 *= 0.08838834764831845f;  // 1/sqrt(128)
      o2 *= 0.08838834764831845f;
      int kv = h >> 2, g = h & 3;
      size_t base = ((((size_t)b * NKVH + kv) * NG + g) * NQ + q) * ND;
      qb[base + d] = f2bf(o1);
      qb[base + d + 64] = f2bf(o2);
    } else {
      int kvh = h - 32;
      size_t base = (((size_t)b * NKVH + kvh) * NQ + q) * ND;
      kb[base + d] = f2bf(o1);
      kb[base + d + 64] = f2bf(o2);
    }
  } else {
    int kvh = h - 40;
    size_t base = (((size_t)b * NKVH + kvh) * NQ + q) * ND;
    vb[base + d] = f2bf(x1);
    vb[base + d + 64] = f2bf(x2);
  }
}

// ---------------- flash attention: KVBLK=32 dbuf, 40KB LDS -> 4 blocks/CU ----------------
// LDS 40960 B:
//   K0@0 K1@8192 (32-key bf16: byte = s*256 + ((d*2)^((s&7)<<4)), s<32)
//   V0@16384 V1@24576 (linear 4x16 subtiles: sb=(j>>2)*8+(d>>4), byte=sb*128+(j&3)*32+(d&15)*2)
//   P @32768 (4 waves x 1KB: byte = wid*1024 + q*64 + ((j2*2)^((q&3)<<4)), j2<32)
//   bias0@36864 bias1@38912 (2KB fp32: byte = q*128 + ((j*4)^((q&7)<<4)), j<32)
// Per-wave: head g=wid over all 32 keys/iter. No forced VGPR cap (launch_bounds(256,2) —
// min-waves=4 provokes pathological 64-VGPR spill, see R7/R11). No vmcnt(0) drains.
template<int NSPL>
__global__ __launch_bounds__(256, 2) void k_attn(
    const unsigned short* __restrict__ qb, const unsigned short* __restrict__ kb,
    const unsigned short* __restrict__ vb, const float* __restrict__ pastK,
    const float* __restrict__ pastV, const float* __restrict__ bias,
    unsigned short* __restrict__ pout, float* __restrict__ pml) {
  __shared__ __align__(16) char lds[40960];
  char* Pl = lds + 32768;
  constexpr int KEYS = NP / NSPL;      // 256 (NS=16)
  constexpr int NSUB = KEYS / 32;      // 8
  int bkv = blockIdx.x;
  int split = blockIdx.y;
  int b = bkv >> 3, kv = bkv & 7;
  int tid = threadIdx.x, lane = tid & 63, wid = tid >> 6;
  int r16 = lane & 15, hi = lane >> 4;

  const unsigned short* qbase = qb + ((((size_t)b * NKVH + kv) * NG + wid) * NQ) * ND;
  bf16x8 qf[4];
#pragma unroll
  for (int kd = 0; kd < 4; ++kd)
    qf[kd] = *(const bf16x8*)&qbase[r16 * ND + kd * 32 + hi * 8];

  float m_run[4], l_lane[4];
  f32x4 oacc[8];
#pragma unroll
  for (int r = 0; r < 4; ++r) { m_run[r] = -1e30f; l_lane[r] = 0.f; }
#pragma unroll
  for (int dt = 0; dt < 8; ++dt) oacc[dt] = {0.f, 0.f, 0.f, 0.f};

  int s0 = split * KEYS;
  const float* Kg = pastK + ((size_t)(b * NKVH + kv) * NP + s0) * ND;
  const float* Vg = pastV + ((size_t)(b * NKVH + kv) * NP + s0) * ND;
  const float* biasrow = bias + (size_t)(b * NQ) * NSEQ;
  int d4 = tid & 31, sr = tid >> 5;
  bool last = (split == NSPL - 1);

  f32x4 rwK[4], rwV[4];
  float br0, br1, bt[4];
  bf16x8 tk, tv;

  auto kissue = [&](int tile) {
    const float* Kn = Kg + (size_t)tile * 32 * ND;
#pragma unroll
    for (int it = 0; it < 4; ++it)
      rwK[it] = *(const f32x4*)&Kn[(size_t)(sr + it * 8) * ND + d4 * 4];
  };
  auto vissue = [&](int tile) {
    const float* Vn = Vg + (size_t)tile * 32 * ND;
#pragma unroll
    for (int it = 0; it < 4; ++it)
      rwV[it] = *(const f32x4*)&Vn[(size_t)(sr + it * 8) * ND + d4 * 4];
  };
  auto bissue = [&](int tile) {
    {
      int e = tid;        int q = e >> 5, j = e & 31;
      br0 = biasrow[(size_t)q * NSEQ + s0 + tile * 32 + j];
    }
    {
      int e = 256 + tid;  int q = e >> 5, j = e & 31;
      br1 = biasrow[(size_t)q * NSEQ + s0 + tile * 32 + j];
    }
  };
  auto kconv = [&](char* Kl) {
#pragma unroll
    for (int it = 0; it < 4; ++it) {
      int s = sr + it * 8;
      uint2 u;
      u.x = cvtpk(rwK[it][0], rwK[it][1]); u.y = cvtpk(rwK[it][2], rwK[it][3]);
      *(uint2*)(Kl + s * 256 + ((d4 * 8) ^ ((s & 7) << 4))) = u;
    }
  };
  auto vconv = [&](char* Vl) {
#pragma unroll
    for (int it = 0; it < 4; ++it) {
      int s = sr + it * 8;
      uint2 u;
      u.x = cvtpk(rwV[it][0], rwV[it][1]); u.y = cvtpk(rwV[it][2], rwV[it][3]);
      *(uint2*)(Vl + ((s >> 2) * 8 + (d4 >> 2)) * 128 + (s & 3) * 32 + (d4 & 3) * 8) = u;
    }
  };
  auto bstore = [&](char* Bb) {
    {
      int e = tid;        int q = e >> 5, j = e & 31;
      *(float*)(Bb + q * 128 + ((j * 4) ^ ((q & 7) << 4))) = br0;
    }
    {
      int e = 256 + tid;  int q = e >> 5, j = e & 31;
      *(float*)(Bb + q * 128 + ((j * 4) ^ ((q & 7) << 4))) = br1;
    }
  };

  f32x4 sc[2];
  auto qk_softmax = [&](char* Kl, char* Bb, bool tail) {
    __builtin_amdgcn_s_setprio(1);
#pragma unroll
    for (int ct = 0; ct < 2; ++ct) {
      f32x4 a = {0.f, 0.f, 0.f, 0.f};
      int s = ct * 16 + r16;
#pragma unroll
      for (int kd = 0; kd < 4; ++kd) {
        bf16x8 kf = *(const bf16x8*)(Kl + s * 256 + ((kd * 64 + hi * 16) ^ ((s & 7) << 4)));
        a = __builtin_amdgcn_mfma_f32_16x16x32_bf16(qf[kd], kf, a, 0, 0, 0);
      }
      sc[ct] = a;
    }
    __builtin_amdgcn_s_setprio(0);
    if (!tail) {
#pragma unroll
      for (int ct = 0; ct < 2; ++ct)
#pragma unroll
        for (int r = 0; r < 4; ++r) {
          int q = hi * 4 + r, j = ct * 16 + r16;
          sc[ct][r] += *(const float*)(Bb + q * 128 + ((j * 4) ^ ((q & 7) << 4)));
        }
    } else {  // tail: keys j = r16 < 16 valid only
#pragma unroll
      for (int ct = 0; ct < 2; ++ct)
#pragma unroll
        for (int r = 0; r < 4; ++r) {
          if (ct == 0) sc[ct][r] += bt[r];
          else         sc[ct][r] = -1e30f;
        }
    }
    float pmax[4];
#pragma unroll
    for (int r = 0; r < 4; ++r)
      pmax[r] = fmaxf(sc[0][r], sc[1][r]);
    bool ok = (pmax[0] <= m_run[0] + 8.f) && (pmax[1] <= m_run[1] + 8.f) &&
              (pmax[2] <= m_run[2] + 8.f) && (pmax[3] <= m_run[3] + 8.f);
    if (!__all(ok)) {   // slow path (rare)
#pragma unroll
      for (int r = 0; r < 4; ++r) {
        float v = pmax[r];
        v = fmaxf(v, __shfl_xor(v, 1));
        v = fmaxf(v, __shfl_xor(v, 2));
        v = fmaxf(v, __shfl_xor(v, 4));
        v = fmaxf(v, __shfl_xor(v, 8));
        float mnew = fmaxf(m_run[r], v);
        float fac = __expf(m_run[r] - mnew);
        m_run[r] = mnew;
        l_lane[r] *= fac;
#pragma unroll
        for (int dt = 0; dt < 8; ++dt) oacc[dt][r] *= fac;
      }
    }
#pragma unroll
    for (int ct = 0; ct < 2; ++ct)
#pragma unroll
      for (int r = 0; r < 4; ++r) {
        float p = __expf(sc[ct][r] - m_run[r]);
        l_lane[r] += p;
        int q = hi * 4 + r, j2 = ct * 16 + r16;
        *(unsigned short*)(Pl + wid * 1024 + q * 64 + ((j2 * 2) ^ ((q & 3) << 4))) = f2bf(p);
      }
  };

  auto pv = [&](char* Vl) {
    unsigned vb32 = (unsigned)(uintptr_t)(void*)Vl;
    bf16x8 pa = *(const bf16x8*)(Pl + wid * 1024 + r16 * 64 +
                                 ((hi * 16) ^ ((r16 & 3) << 4)));
#pragma unroll
    for (int dh = 0; dh < 2; ++dh) {
      unsigned long long rr[8];
#pragma unroll
      for (int dq = 0; dq < 4; ++dq) {
        int sA = hi * 16 + dh * 4 + dq;
        TRREAD(rr[dq * 2],     vb32 + sA * 128 + r16 * 8);
        TRREAD(rr[dq * 2 + 1], vb32 + (sA + 8) * 128 + r16 * 8);
      }
      LGKM0();
      __builtin_amdgcn_sched_barrier(0);
      __builtin_amdgcn_s_setprio(1);
#pragma unroll
      for (int dq = 0; dq < 4; ++dq) {
        union { unsigned long long u[2]; bf16x8 v; } cc;
        cc.u[0] = rr[dq * 2]; cc.u[1] = rr[dq * 2 + 1];
        oacc[dh * 4 + dq] = __builtin_amdgcn_mfma_f32_16x16x32_bf16(pa, cc.v, oacc[dh * 4 + dq], 0, 0, 0);
      }
      __builtin_amdgcn_s_setprio(0);
    }
  };

  // ---- prologue: tile0 -> buf0 ----
  kissue(0);
  vissue(0);
  bissue(0);
  kconv(lds + 0);
  vconv(lds + 16384);
  bstore(lds + 36864);
  LGKM0();

  // ---- main loop: no vmcnt(0) drains in steady state ----
  int cur = 0;
  for (int sub = 0; sub < NSUB; ++sub) {
    char* KlC = lds + cur * 8192;
    char* VlC = lds + 16384 + cur * 8192;
    char* BbC = lds + 36864 + cur * 2048;
    char* KlN = lds + (cur ^ 1) * 8192;
    char* VlN = lds + 16384 + (cur ^ 1) * 8192;
    char* BbN = lds + 36864 + (cur ^ 1) * 2048;
    SBAR();                                  // buf[cur] ready
    bool pf = (sub + 1 < NSUB);
    if (pf) {                                // issue next K + bias (V issued mid-iter)
      kissue(sub + 1);
      bissue(sub + 1);
    } else if (last) {                       // issue tail (16 new bf16 keys)
      int s = tid >> 4, d8 = tid & 15;
      const unsigned short* Kn = kb + (((size_t)b * NKVH + kv) * NQ) * ND;
      const unsigned short* Vn = vb + (((size_t)b * NKVH + kv) * NQ) * ND;
      tk = *(const bf16x8*)&Kn[s * ND + d8 * 8];
      tv = *(const bf16x8*)&Vn[s * ND + d8 * 8];
#pragma unroll
      for (int r = 0; r < 4; ++r)
        bt[r] = biasrow[(size_t)(hi * 4 + r) * NSEQ + NP + r16];
    }
    qk_softmax(KlC, BbC, false);
    if (pf) {
      kconv(KlN);                            // counted wait: K only (bias older done w/ it)
      vissue(sub + 1);                       // V flies under pv
    } else if (last) {
      int s = tid >> 4, d8 = tid & 15;
      *(bf16x8*)(KlN + s * 256 + ((d8 * 16) ^ ((s & 7) << 4))) = tk;
    }
    pv(VlC);
    if (pf) {
      vconv(VlN);                            // counted wait: V
      bstore(BbN);
    } else if (last) {
      int s = tid >> 4, d8 = tid & 15;
      *(bf16x8*)(VlN + ((s >> 2) * 8 + (d8 >> 1)) * 128 + (s & 3) * 32 + (d8 & 1) * 16) = tv;
    }
    LGKM0();                                 // ds writes visible before next SBAR
    if (pf || last) cur ^= 1;
  }
  if (last) {                                // tail keys in buf[cur]
    SBAR();
    qk_softmax(lds + cur * 8192, (char*)0, true);
    pv(lds + 16384 + cur * 8192);
  }

  // ---- epilogue: reduce l partials; bounce oacc through lds; coalesced stores ----
  float l_run[4];
#pragma unroll
  for (int r = 0; r < 4; ++r) {
    float s = l_lane[r];
    s += __shfl_xor(s, 1);
    s += __shfl_xor(s, 2);
    s += __shfl_xor(s, 4);
    s += __shfl_xor(s, 8);
    l_run[r] = s;
  }
  SBAR();
  char* My = lds + wid * 4096;
#pragma unroll
  for (int dt = 0; dt < 8; ++dt)
#pragma unroll
    for (int r = 0; r < 4; ++r)
      *(unsigned short*)(My + (hi * 4 + r) * 256 + (dt * 16 + r16) * 2) = f2bf(oacc[dt][r]);
  LGKM0();
  const int NROW = NB * NKVH * NG * NQ;      // 8192
  size_t rowbase = ((size_t)(b * NKVH + kv) * NG + wid) * NQ;
  unsigned short* po = pout + ((size_t)split * NROW + rowbase) * ND;
#pragma unroll
  for (int it = 0; it < 4; ++it) {
    int row = it * 4 + (lane >> 4);
    uint4 vv = *(uint4*)(My + row * 256 + r16 * 16);
    *(uint4*)&po[(size_t)row * ND + r16 * 8] = vv;
  }
  if (r16 == 0) {
#pragma unroll
    for (int r = 0; r < 4; ++r) {
      size_t idx = ((size_t)split * NROW + rowbase + hi * 4 + r) * 2;
      pml[idx] = m_run[r];
      pml[idx + 1] = l_run[r];
    }
  }
}

// ---------------- combine split partials -> bf16 A for the Wo GEMM ----------------
template<int NSPL>
__global__ __launch_bounds__(256) void k_combine(
    const unsigned short* __restrict__ pout, const float* __restrict__ pml,
    unsigned short* __restrict__ Aatt) {
  const int NROW = NB * NKVH * NG * NQ;  // 8192
  int row = blockIdx.x * 2 + (threadIdx.x >> 7);
  int d = threadIdx.x & 127;
  float mv[NSPL], lv[NSPL];
  float M = -1e30f;
#pragma unroll
  for (int c = 0; c < NSPL; ++c) {
    mv[c] = pml[((size_t)c * NROW + row) * 2];
    lv[c] = pml[((size_t)c * NROW + row) * 2 + 1];
    M = fmaxf(M, mv[c]);
  }
  float L = 0.f, acc = 0.f;
#pragma unroll
  for (int c = 0; c < NSPL; ++c) {
    float w = __expf(mv[c] - M);
    L += lv[c] * w;
    acc += bf2f(pout[((size_t)c * NROW + row) * ND + d]) * w;
  }
  float o = acc / L;
  int q = row & 15, g = (row >> 4) & 3, kvh = (row >> 6) & 7, b = row >> 9;
  Aatt[(size_t)(b * NQ + q) * NHID + (kvh * NG + g) * ND + d] = f2bf(o);
}

// ---------------- reduce Wo partials -> d_out ----------------
__global__ __launch_bounds__(256) void k_red(const float* __restrict__ part,
                                             float* __restrict__ out) {
  int i = blockIdx.x * 256 + threadIdx.x;
  float s = 0.f;
#pragma unroll
  for (int c = 0; c < SPLITK; ++c) s += part[(size_t)c * (NM * NHID) + i];
  out[i] = s;
}

extern "C" void kernel_launch(void* const* d_in, const int* in_sizes, int n_in,
                              void* d_out, int out_size, void* d_ws, size_t ws_size,
                              hipStream_t stream) {
  const float* hidden = (const float*)d_in[0];
  const void* pos = d_in[1];
  const float* pastK = (const float*)d_in[2];
  const float* pastV = (const float*)d_in[3];
  const float* bias = (const float*)d_in[4];
  const float* Wq = (const float*)d_in[5];
  const float* Wk = (const float*)d_in[6];
  const float* Wv = (const float*)d_in[7];
  const float* Wo = (const float*)d_in[8];
  float* out = (float*)d_out;

  char* ws = (char*)d_ws;
  size_t off = 0;
  auto alloc = [&](size_t bytes) {
    char* p = ws + off;
    off += (bytes + 255) & ~(size_t)255;
    return p;
  };
  unsigned short* hb   = (unsigned short*)alloc((size_t)NM * NHID * 2);
  unsigned short* qb   = (unsigned short*)alloc((size_t)NB * NKVH * NG * NQ * ND * 2);
  unsigned short* kb   = (unsigned short*)alloc((size_t)NB * NKVH * NQ * ND * 2);
  unsigned short* vb   = (unsigned short*)alloc((size_t)NB * NKVH * NQ * ND * 2);
  unsigned short* Aatt = (unsigned short*)alloc((size_t)NM * NHID * 2);

  // Union region: GEMM partials (phases 1 & 5) alias attn pml+pout (phases 3-4).
  size_t ml16 = (size_t)16 * 8192 * 2 * 4;                    // 1 MB
  size_t po16 = (size_t)16 * 8192 * ND * 2;                   // 33.5 MB
  size_t partB = (size_t)SPLITK * NM * N_QKV * 4;             // 25.2 MB
  size_t need16 = (ml16 + po16 > partB) ? ml16 + po16 : partB;
  int NSP = (ws_size >= off + need16 + 4096) ? 16 : 8;
  float* pml = (float*)(ws + off);
  unsigned short* pout = (unsigned short*)(ws + off + (NSP == 16 ? ml16 : ml16 / 2));
  float* part = (float*)(ws + off);

  k_cvt<<<512, 256, 0, stream>>>(hidden, hb, NM * NHID / 4);
  k_gemm<2><<<dim3(96, SPLITK), 256, 0, stream>>>(hb, NHID, Wq, Wk, Wv, 4096, 5120,
                                                  N_QKV, NHID / SPLITK, part);
  k_rope<<<1536, 256, 0, stream>>>(part, pos, qb, kb, vb);
  if (NSP == 16) {
    k_attn<16><<<dim3(64, 16), 256, 0, stream>>>(qb, kb, vb, pastK, pastV, bias, pout, pml);
    k_combine<16><<<4096, 256, 0, stream>>>(pout, pml, Aatt);
  } else {
    k_attn<8><<<dim3(64, 8), 256, 0, stream>>>(qb, kb, vb, pastK, pastV, bias, pout, pml);
    k_combine<8><<<4096, 256, 0, stream>>>(pout, pml, Aatt);
  }
  k_gemm<2><<<dim3(64, SPLITK), 256, 0, stream>>>(Aatt, NHID, Wo, Wo, Wo, 4096, 8192,
                                                  NHID, NHID / SPLITK, part);
  k_red<<<2048, 256, 0, stream>>>(part, out);
}